// Round 1
// baseline (412.985 us; speedup 1.0000x reference)
//
#include <hip/hip_runtime.h>
#include <hip/hip_bf16.h>

#define B_  128
#define S_  512
#define H_  64
#define E_  64
#define G3  192   // 3*H

__device__ __forceinline__ float sigmoidf_(float x) {
    return 1.0f / (1.0f + __expf(-x));
}

__device__ __forceinline__ float tanh_fast(float x) {
    x = fminf(fmaxf(x, -15.0f), 15.0f);
    const float e = __expf(2.0f * x);
    return (e - 1.0f) / (e + 1.0f);
}

// One block per (batch row, direction). 192 threads: thread j owns gate-column j.
//   j in [0,64):    update gate z_j
//   j in [64,128):  reset gate r_{j-64}
//   j in [128,192): candidate + state update for unit j-128
__global__ __launch_bounds__(192) void gru_scan_kernel(
    const int*   __restrict__ inputs,   // [B,S]
    const float* __restrict__ emb,      // [V,E]
    const float* __restrict__ Wf, const float* __restrict__ Uf,
    const float* __restrict__ bif, const float* __restrict__ brf,
    const float* __restrict__ Wb, const float* __restrict__ Ub,
    const float* __restrict__ bib, const float* __restrict__ brb,
    float* __restrict__ gru_out)        // [B,S,2H]
{
    const int b   = blockIdx.x >> 1;
    const int dir = blockIdx.x & 1;
    const int j   = threadIdx.x;

    const float* W  = dir ? Wb  : Wf;
    const float* U  = dir ? Ub  : Uf;
    const float* bi = dir ? bib : bif;
    const float* br = dir ? brb : brf;

    __shared__ int s_idx[S_];
    __shared__ __align__(16) float s_x[E_];
    __shared__ __align__(16) float s_h[H_];
    __shared__ float s_z[H_];
    __shared__ float s_r[H_];

    for (int t = j; t < S_; t += 192) s_idx[t] = inputs[b * S_ + t];
    if (j < H_) s_h[j] = 0.0f;

    // Weight columns in registers: 64 + 64 VGPRs per thread.
    float w[E_], u[H_];
    #pragma unroll
    for (int e = 0; e < E_; ++e) w[e] = W[e * G3 + j];
    #pragma unroll
    for (int e = 0; e < H_; ++e) u[e] = U[e * G3 + j];
    const float bij = bi[j];
    const float brj = br[j];

    __syncthreads();

    for (int t = 0; t < S_; ++t) {
        const int tt  = dir ? (S_ - 1 - t) : t;
        const int tok = s_idx[tt];

        // stage embedding row for this step
        if (j < E_) s_x[j] = emb[(size_t)tok * E_ + j];
        __syncthreads();   // (A) s_x ready; s_h from previous step ready

        // xw_j = bi_j + x . W[:,j]   ;   rec_j = br_j + h . U[:,j]
        float ax = bij, ah = brj;
        const float4* xs4 = (const float4*)s_x;
        const float4* hs4 = (const float4*)s_h;
        #pragma unroll
        for (int e4 = 0; e4 < E_ / 4; ++e4) {
            const float4 xv = xs4[e4];
            const float4 hv = hs4[e4];
            ax = fmaf(xv.x, w[4*e4+0], ax);
            ax = fmaf(xv.y, w[4*e4+1], ax);
            ax = fmaf(xv.z, w[4*e4+2], ax);
            ax = fmaf(xv.w, w[4*e4+3], ax);
            ah = fmaf(hv.x, u[4*e4+0], ah);
            ah = fmaf(hv.y, u[4*e4+1], ah);
            ah = fmaf(hv.z, u[4*e4+2], ah);
            ah = fmaf(hv.w, u[4*e4+3], ah);
        }

        if (j < H_) {
            s_z[j] = sigmoidf_(ax + ah);          // update gate
        } else if (j < 2 * H_) {
            s_r[j - H_] = sigmoidf_(ax + ah);     // reset gate
        }
        __syncthreads();   // (B) all dot-reads of s_x/s_h done; z,r visible

        if (j >= 2 * H_) {
            const int   uu   = j - 2 * H_;
            const float r    = s_r[uu];
            const float z    = s_z[uu];
            const float hh   = tanh_fast(ax + r * ah);   // candidate
            const float hold = s_h[uu];
            const float hnew = z * hold + (1.0f - z) * hh;
            const float res  = (tok != 0) ? hnew : hold; // mask_zero carry
            s_h[uu] = res;
            gru_out[(size_t)(b * S_ + tt) * (2 * H_) + dir * H_ + uu] = res;
        }
    }
}

// x1 = sigmoid(gru_out @ w1 + b1), x2 = sigmoid(gru_out @ w2 + b2)
__global__ __launch_bounds__(256) void head_kernel(
    const float* __restrict__ gru,      // [B*S, 2H]
    const float* __restrict__ w1, const float* __restrict__ b1,
    const float* __restrict__ w2, const float* __restrict__ b2,
    float* __restrict__ x1, float* __restrict__ x2)
{
    __shared__ __align__(16) float s_w1[2 * H_];
    __shared__ __align__(16) float s_w2[2 * H_];
    const int tid = threadIdx.x;
    if (tid < 2 * H_)      s_w1[tid]          = w1[tid];
    else                   s_w2[tid - 2 * H_] = w2[tid - 2 * H_];
    __syncthreads();

    const int i = blockIdx.x * 256 + tid;   // row index in [0, B*S)
    const float4* g4 = (const float4*)(gru + (size_t)i * (2 * H_));
    float a1 = b1[0], a2 = b2[0];
    #pragma unroll
    for (int k = 0; k < (2 * H_) / 4; ++k) {
        const float4 v  = g4[k];
        const float4 q1 = ((const float4*)s_w1)[k];
        const float4 q2 = ((const float4*)s_w2)[k];
        a1 += v.x * q1.x + v.y * q1.y + v.z * q1.z + v.w * q1.w;
        a2 += v.x * q2.x + v.y * q2.y + v.z * q2.z + v.w * q2.w;
    }
    x1[i] = sigmoidf_(a1);
    x2[i] = sigmoidf_(a2);
}

extern "C" void kernel_launch(void* const* d_in, const int* in_sizes, int n_in,
                              void* d_out, int out_size, void* d_ws, size_t ws_size,
                              hipStream_t stream) {
    (void)in_sizes; (void)n_in; (void)d_ws; (void)ws_size; (void)out_size;

    const int*   inputs = (const int*)  d_in[0];
    const float* emb    = (const float*)d_in[1];
    const float* Wf     = (const float*)d_in[2];
    const float* Uf     = (const float*)d_in[3];
    const float* bif    = (const float*)d_in[4];
    const float* brf    = (const float*)d_in[5];
    const float* Wb     = (const float*)d_in[6];
    const float* Ub     = (const float*)d_in[7];
    const float* bib    = (const float*)d_in[8];
    const float* brb    = (const float*)d_in[9];
    const float* w1     = (const float*)d_in[10];
    const float* b1     = (const float*)d_in[11];
    const float* w2     = (const float*)d_in[12];
    const float* b2     = (const float*)d_in[13];

    float* out = (float*)d_out;
    float* x1  = out;                       // [B*S]
    float* x2  = out + (size_t)B_ * S_;     // [B*S]
    float* gru = out + (size_t)2 * B_ * S_; // [B*S, 2H]

    // 256 independent recurrences: (batch b, direction) -> one block, one CU.
    gru_scan_kernel<<<B_ * 2, 192, 0, stream>>>(
        inputs, emb, Wf, Uf, bif, brf, Wb, Ub, bib, brb, gru);

    head_kernel<<<(B_ * S_) / 256, 256, 0, stream>>>(gru, w1, b1, w2, b2, x1, x2);
}

// Round 2
// 402.753 us; speedup vs baseline: 1.0254x; 1.0254x over previous
//
#include <hip/hip_runtime.h>
#include <hip/hip_bf16.h>

#define B_  128
#define S_  512
#define H_  64
#define E_  64
#define G3  192   // 3*H
#define V_  4996
#define VCHUNK 32

__device__ __forceinline__ float sigmoidf_(float x) {
    return 1.0f / (1.0f + __expf(-x));
}

__device__ __forceinline__ float tanh_fast(float x) {
    x = fminf(fmaxf(x, -15.0f), 15.0f);
    const float e = __expf(2.0f * x);
    return (e - 1.0f) / (e + 1.0f);
}

// ---------------------------------------------------------------------------
// Kernel 1: pre-project the embedding table through the input kernels.
//   proj[dir][v][j] = sum_e emb[v][e] * W_dir[e][j] + bi_dir[j]
// Fully parallel; removes the x@W dot (and the emb gather) from the scan.
// ---------------------------------------------------------------------------
__global__ __launch_bounds__(192) void proj_kernel(
    const float* __restrict__ emb,
    const float* __restrict__ Wf, const float* __restrict__ bif,
    const float* __restrict__ Wb, const float* __restrict__ bib,
    float* __restrict__ proj)            // [2][V][192]
{
    const int dir = blockIdx.y;
    const float* W  = dir ? Wb  : Wf;
    const float* bi = dir ? bib : bif;
    const int v0 = blockIdx.x * VCHUNK;
    const int j  = threadIdx.x;
    const int nrows = min(VCHUNK, V_ - v0);

    __shared__ __align__(16) float s_e[VCHUNK * E_];
    for (int i = j; i < nrows * E_; i += 192) s_e[i] = emb[(size_t)v0 * E_ + i];

    float wcol[E_];
    #pragma unroll
    for (int e = 0; e < E_; ++e) wcol[e] = W[e * G3 + j];
    const float bij = bi[j];
    __syncthreads();

    for (int r = 0; r < nrows; ++r) {
        const float4* x4 = (const float4*)(s_e + r * E_);
        float a0 = 0.f, a1 = 0.f, a2 = 0.f, a3 = 0.f;
        #pragma unroll
        for (int e4 = 0; e4 < 16; e4 += 4) {
            float4 h0 = x4[e4], h1 = x4[e4+1], h2 = x4[e4+2], h3 = x4[e4+3];
            a0 = fmaf(h0.x, wcol[4*e4+ 0], a0); a0 = fmaf(h0.y, wcol[4*e4+ 1], a0);
            a0 = fmaf(h0.z, wcol[4*e4+ 2], a0); a0 = fmaf(h0.w, wcol[4*e4+ 3], a0);
            a1 = fmaf(h1.x, wcol[4*e4+ 4], a1); a1 = fmaf(h1.y, wcol[4*e4+ 5], a1);
            a1 = fmaf(h1.z, wcol[4*e4+ 6], a1); a1 = fmaf(h1.w, wcol[4*e4+ 7], a1);
            a2 = fmaf(h2.x, wcol[4*e4+ 8], a2); a2 = fmaf(h2.y, wcol[4*e4+ 9], a2);
            a2 = fmaf(h2.z, wcol[4*e4+10], a2); a2 = fmaf(h2.w, wcol[4*e4+11], a2);
            a3 = fmaf(h3.x, wcol[4*e4+12], a3); a3 = fmaf(h3.y, wcol[4*e4+13], a3);
            a3 = fmaf(h3.z, wcol[4*e4+14], a3); a3 = fmaf(h3.w, wcol[4*e4+15], a3);
        }
        proj[((size_t)dir * V_ + v0 + r) * G3 + j] = ((a0 + a1) + (a2 + a3)) + bij;
    }
}

// Kernel 2: transpose recurrent kernels so scan threads can float4-load columns.
//   Ut[dir][j][e] = U_dir[e][j]
__global__ void utrans_kernel(const float* __restrict__ Uf,
                              const float* __restrict__ Ub,
                              float* __restrict__ Ut)   // [2][192][64]
{
    const int dir = blockIdx.x;
    const float* U = dir ? Ub : Uf;
    float* o = Ut + (size_t)dir * G3 * H_;
    for (int k = threadIdx.x; k < G3 * H_; k += blockDim.x) {
        const int j = k / H_, e = k % H_;
        o[k] = U[e * G3 + j];
    }
}

// ---------------------------------------------------------------------------
// Kernel 3: the sequential scan. One block per (batch row, direction).
// 192 threads: thread j owns recurrent column j (z | r | candidate).
// ---------------------------------------------------------------------------
__global__ __launch_bounds__(192) void gru_scan2(
    const int*   __restrict__ inputs,   // [B,S]
    const float* __restrict__ proj,     // [2][V][192]
    const float* __restrict__ Ut,       // [2][192][64]
    const float* __restrict__ brf, const float* __restrict__ brb,
    float* __restrict__ gru_out)        // [B,S,2H]
{
    const int b   = blockIdx.x >> 1;
    const int dir = blockIdx.x & 1;
    const int j   = threadIdx.x;
    const float* eproj = proj + (size_t)dir * V_ * G3;
    const float* br    = dir ? brb : brf;

    __shared__ int s_idx[S_];
    __shared__ __align__(16) float s_h[H_];
    __shared__ float s_gzr[2 * H_];     // [0:64)=z, [64:128)=r

    for (int t = j; t < S_; t += 192) s_idx[t] = inputs[b * S_ + t];
    if (j < H_) s_h[j] = 0.0f;

    // Recurrent column in registers: 16 float4 = 64 VGPRs.
    float4 u4[16];
    {
        const float4* p = (const float4*)(Ut + ((size_t)dir * G3 + j) * H_);
        #pragma unroll
        for (int e4 = 0; e4 < 16; ++e4) u4[e4] = p[e4];
    }
    const float brj = br[j];
    __syncthreads();

    int   tok   = s_idx[dir ? (S_ - 1) : 0];
    float xw    = eproj[(size_t)tok * G3 + j];   // includes input bias
    float hprev = 0.0f;                          // wave-2's own unit state

    for (int t = 0; t < S_; ++t) {
        const int tt = dir ? (S_ - 1 - t) : t;

        // prefetch next step's projected input (off critical path)
        int ntok = 0; float xw_next = 0.0f;
        if (t + 1 < S_) {
            ntok    = s_idx[dir ? (S_ - 2 - t) : (t + 1)];
            xw_next = eproj[(size_t)ntok * G3 + j];
        }

        __syncthreads();   // (A) s_h from previous step visible

        // rec_j = br_j + h . U[:,j]  — 4 independent FMA chains
        const float4* h4 = (const float4*)s_h;
        float a0 = 0.f, a1 = 0.f, a2 = 0.f, a3 = 0.f;
        #pragma unroll
        for (int e4 = 0; e4 < 16; e4 += 4) {
            float4 h0 = h4[e4], h1 = h4[e4+1], h2 = h4[e4+2], h3 = h4[e4+3];
            a0 = fmaf(h0.x, u4[e4  ].x, a0); a0 = fmaf(h0.y, u4[e4  ].y, a0);
            a0 = fmaf(h0.z, u4[e4  ].z, a0); a0 = fmaf(h0.w, u4[e4  ].w, a0);
            a1 = fmaf(h1.x, u4[e4+1].x, a1); a1 = fmaf(h1.y, u4[e4+1].y, a1);
            a1 = fmaf(h1.z, u4[e4+1].z, a1); a1 = fmaf(h1.w, u4[e4+1].w, a1);
            a2 = fmaf(h2.x, u4[e4+2].x, a2); a2 = fmaf(h2.y, u4[e4+2].y, a2);
            a2 = fmaf(h2.z, u4[e4+2].z, a2); a2 = fmaf(h2.w, u4[e4+2].w, a2);
            a3 = fmaf(h3.x, u4[e4+3].x, a3); a3 = fmaf(h3.y, u4[e4+3].y, a3);
            a3 = fmaf(h3.z, u4[e4+3].z, a3); a3 = fmaf(h3.w, u4[e4+3].w, a3);
        }
        const float ah = ((a0 + a1) + (a2 + a3)) + brj;

        if (j < 2 * H_) s_gzr[j] = sigmoidf_(xw + ah);   // z | r

        __syncthreads();   // (B) z,r visible; all reads of s_h/s_x done

        if (j >= 2 * H_) {
            const int   uu   = j - 2 * H_;
            const float r    = s_gzr[H_ + uu];
            const float z    = s_gzr[uu];
            const float hh   = tanh_fast(xw + r * ah);
            const float hnew = z * hprev + (1.0f - z) * hh;
            const float res  = (tok != 0) ? hnew : hprev;   // mask_zero carry
            hprev = res;
            s_h[uu] = res;
            gru_out[((size_t)(b * S_ + tt)) * (2 * H_) + dir * H_ + uu] = res;
        }

        tok = ntok;
        xw  = xw_next;
    }
}

// x1 = sigmoid(gru_out @ w1 + b1), x2 = sigmoid(gru_out @ w2 + b2)
__global__ __launch_bounds__(256) void head_kernel(
    const float* __restrict__ gru,      // [B*S, 2H]
    const float* __restrict__ w1, const float* __restrict__ b1,
    const float* __restrict__ w2, const float* __restrict__ b2,
    float* __restrict__ x1, float* __restrict__ x2)
{
    __shared__ __align__(16) float s_w1[2 * H_];
    __shared__ __align__(16) float s_w2[2 * H_];
    const int tid = threadIdx.x;
    if (tid < 2 * H_)      s_w1[tid]          = w1[tid];
    else                   s_w2[tid - 2 * H_] = w2[tid - 2 * H_];
    __syncthreads();

    const int i = blockIdx.x * 256 + tid;
    const float4* g4 = (const float4*)(gru + (size_t)i * (2 * H_));
    float a1 = b1[0], a2 = b2[0];
    #pragma unroll
    for (int k = 0; k < (2 * H_) / 4; ++k) {
        const float4 v  = g4[k];
        const float4 q1 = ((const float4*)s_w1)[k];
        const float4 q2 = ((const float4*)s_w2)[k];
        a1 += v.x * q1.x + v.y * q1.y + v.z * q1.z + v.w * q1.w;
        a2 += v.x * q2.x + v.y * q2.y + v.z * q2.z + v.w * q2.w;
    }
    x1[i] = sigmoidf_(a1);
    x2[i] = sigmoidf_(a2);
}

extern "C" void kernel_launch(void* const* d_in, const int* in_sizes, int n_in,
                              void* d_out, int out_size, void* d_ws, size_t ws_size,
                              hipStream_t stream) {
    (void)in_sizes; (void)n_in; (void)ws_size; (void)out_size;

    const int*   inputs = (const int*)  d_in[0];
    const float* emb    = (const float*)d_in[1];
    const float* Wf     = (const float*)d_in[2];
    const float* Uf     = (const float*)d_in[3];
    const float* bif    = (const float*)d_in[4];
    const float* brf    = (const float*)d_in[5];
    const float* Wb     = (const float*)d_in[6];
    const float* Ub     = (const float*)d_in[7];
    const float* bib    = (const float*)d_in[8];
    const float* brb    = (const float*)d_in[9];
    const float* w1     = (const float*)d_in[10];
    const float* b1     = (const float*)d_in[11];
    const float* w2     = (const float*)d_in[12];
    const float* b2     = (const float*)d_in[13];

    float* out = (float*)d_out;
    float* x1  = out;                       // [B*S]
    float* x2  = out + (size_t)B_ * S_;     // [B*S]
    float* gru = out + (size_t)2 * B_ * S_; // [B*S, 2H]

    // workspace: proj [2][V][192] floats, then Ut [2][192][64] floats (~7.77 MB)
    float* proj = (float*)d_ws;
    float* Ut   = proj + (size_t)2 * V_ * G3;

    proj_kernel<<<dim3((V_ + VCHUNK - 1) / VCHUNK, 2), 192, 0, stream>>>(
        emb, Wf, bif, Wb, bib, proj);
    utrans_kernel<<<2, 256, 0, stream>>>(Uf, Ub, Ut);

    gru_scan2<<<B_ * 2, 192, 0, stream>>>(inputs, proj, Ut, brf, brb, gru);

    head_kernel<<<(B_ * S_) / 256, 256, 0, stream>>>(gru, w1, b1, w2, b2, x1, x2);
}

// Round 3
// 319.454 us; speedup vs baseline: 1.2928x; 1.2608x over previous
//
#include <hip/hip_runtime.h>
#include <hip/hip_bf16.h>

#define B_  128
#define S_  512
#define H_  64
#define E_  64
#define G3  192   // 3*H
#define V_  4996
#define VCHUNK 32

typedef float f32x2 __attribute__((ext_vector_type(2)));
typedef float f32x4 __attribute__((ext_vector_type(4)));

__device__ __forceinline__ float sigmoidf_(float x) {
    return 1.0f / (1.0f + __expf(-x));
}

__device__ __forceinline__ float tanh_fast(float x) {
    x = fminf(fmaxf(x, -15.0f), 15.0f);
    const float e = __expf(2.0f * x);
    return (e - 1.0f) / (e + 1.0f);
}

// ---------------------------------------------------------------------------
// Kernel 1: pre-project the embedding table through the input kernels.
//   proj[dir][v][j] = sum_e emb[v][e] * W_dir[e][j] + bi_dir[j]
// ---------------------------------------------------------------------------
__global__ __launch_bounds__(192) void proj_kernel(
    const float* __restrict__ emb,
    const float* __restrict__ Wf, const float* __restrict__ bif,
    const float* __restrict__ Wb, const float* __restrict__ bib,
    float* __restrict__ proj)            // [2][V][192]
{
    const int dir = blockIdx.y;
    const float* W  = dir ? Wb  : Wf;
    const float* bi = dir ? bib : bif;
    const int v0 = blockIdx.x * VCHUNK;
    const int j  = threadIdx.x;
    const int nrows = min(VCHUNK, V_ - v0);

    __shared__ __align__(16) float s_e[VCHUNK * E_];
    for (int i = j; i < nrows * E_; i += 192) s_e[i] = emb[(size_t)v0 * E_ + i];

    float wcol[E_];
    #pragma unroll
    for (int e = 0; e < E_; ++e) wcol[e] = W[e * G3 + j];
    const float bij = bi[j];
    __syncthreads();

    for (int r = 0; r < nrows; ++r) {
        const float4* x4 = (const float4*)(s_e + r * E_);
        float a0 = 0.f, a1 = 0.f, a2 = 0.f, a3 = 0.f;
        #pragma unroll
        for (int e4 = 0; e4 < 16; e4 += 4) {
            float4 h0 = x4[e4], h1 = x4[e4+1], h2 = x4[e4+2], h3 = x4[e4+3];
            a0 = fmaf(h0.x, wcol[4*e4+ 0], a0); a0 = fmaf(h0.y, wcol[4*e4+ 1], a0);
            a0 = fmaf(h0.z, wcol[4*e4+ 2], a0); a0 = fmaf(h0.w, wcol[4*e4+ 3], a0);
            a1 = fmaf(h1.x, wcol[4*e4+ 4], a1); a1 = fmaf(h1.y, wcol[4*e4+ 5], a1);
            a1 = fmaf(h1.z, wcol[4*e4+ 6], a1); a1 = fmaf(h1.w, wcol[4*e4+ 7], a1);
            a2 = fmaf(h2.x, wcol[4*e4+ 8], a2); a2 = fmaf(h2.y, wcol[4*e4+ 9], a2);
            a2 = fmaf(h2.z, wcol[4*e4+10], a2); a2 = fmaf(h2.w, wcol[4*e4+11], a2);
            a3 = fmaf(h3.x, wcol[4*e4+12], a3); a3 = fmaf(h3.y, wcol[4*e4+13], a3);
            a3 = fmaf(h3.z, wcol[4*e4+14], a3); a3 = fmaf(h3.w, wcol[4*e4+15], a3);
        }
        proj[((size_t)dir * V_ + v0 + r) * G3 + j] = ((a0 + a1) + (a2 + a3)) + bij;
    }
}

// Kernel 2: transpose recurrent kernels: Ut[dir][j][e] = U_dir[e][j]
__global__ void utrans_kernel(const float* __restrict__ Uf,
                              const float* __restrict__ Ub,
                              float* __restrict__ Ut)   // [2][192][64]
{
    const int dir = blockIdx.x;
    const float* U = dir ? Ub : Uf;
    float* o = Ut + (size_t)dir * G3 * H_;
    for (int k = threadIdx.x; k < G3 * H_; k += blockDim.x) {
        const int j = k / H_, e = k % H_;
        o[k] = U[e * G3 + j];
    }
}

// ---------------------------------------------------------------------------
// Kernel 3: the sequential scan. One block per (batch row, direction).
// 256 threads = 4 waves; wave wv owns units [16*wv, 16*wv+16).
// Within a wave: lane = g*16 + ul, g=0:z  g=1:r  g=2:candidate  g=3:dup(c).
// z,r -> candidate exchange is intra-wave shfl (no barrier); h is
// double-buffered in LDS so only ONE barrier per step.
// ---------------------------------------------------------------------------
__global__ __launch_bounds__(256, 1) void gru_scan3(
    const int*   __restrict__ inputs,   // [B,S]
    const float* __restrict__ proj,     // [2][V][192]
    const float* __restrict__ Ut,       // [2][192][64]
    const float* __restrict__ brf, const float* __restrict__ brb,
    float* __restrict__ gru_out)        // [B,S,2H]
{
    const int b    = blockIdx.x >> 1;
    const int dir  = blockIdx.x & 1;
    const int lane = threadIdx.x & 63;
    const int wv   = threadIdx.x >> 6;     // 0..3
    const int g    = lane >> 4;            // 0=z, 1=r, 2=c, 3=dup
    const int ul   = lane & 15;
    const int unit = wv * 16 + ul;         // 0..63
    const int j    = (g >= 2 ? 2 : g) * H_ + unit;   // gate column

    const float* eproj = proj + (size_t)dir * V_ * G3;
    const float* br    = dir ? brb : brf;

    __shared__ int s_idx[S_];
    __shared__ __align__(16) float s_hbuf[2][H_];

    for (int t = threadIdx.x; t < S_; t += 256) s_idx[t] = inputs[b * S_ + t];
    if (threadIdx.x < H_) s_hbuf[0][threadIdx.x] = 0.0f;

    // Recurrent column in registers: 16 f32x4 = 64 VGPRs, pinned so the
    // compiler cannot rematerialize the global loads inside the loop.
    f32x4 u4[16];
    {
        const f32x4* p = (const f32x4*)(Ut + ((size_t)dir * G3 + j) * H_);
        #pragma unroll
        for (int k = 0; k < 16; ++k) u4[k] = p[k];
        #pragma unroll
        for (int k = 0; k < 16; ++k) asm volatile("" : "+v"(u4[k]));
    }
    const float brj   = br[j];
    float       hprev = 0.0f;
    __syncthreads();

    int   tok = s_idx[dir ? (S_ - 1) : 0];
    float xw  = eproj[(size_t)tok * G3 + j];

    for (int t = 0; t < S_; ++t) {
        const int tt = dir ? (S_ - 1 - t) : t;

        // prefetch next step's projected input (off critical path)
        int ntok = 0; float xw_next = 0.0f;
        if (t + 1 < S_) {
            ntok    = s_idx[dir ? (S_ - 2 - t) : (t + 1)];
            xw_next = eproj[(size_t)ntok * G3 + j];
        }

        // rec_j = br_j + h . U[:,j] — packed f32x2 FMAs, 4 indep chains
        const f32x4* h4 = (const f32x4*)s_hbuf[t & 1];
        f32x2 aA = {0.f, 0.f}, aB = {0.f, 0.f}, aC = {0.f, 0.f}, aD = {0.f, 0.f};
        #pragma unroll
        for (int k = 0; k < 16; k += 2) {
            const f32x4 h0 = h4[k], h1 = h4[k + 1];
            aA += h0.xy * u4[k].xy;
            aB += h0.zw * u4[k].zw;
            aC += h1.xy * u4[k + 1].xy;
            aD += h1.zw * u4[k + 1].zw;
        }
        const f32x2 sv = (aA + aB) + (aC + aD);
        const float ah = sv.x + sv.y + brj;

        const float gate = sigmoidf_(xw + ah);       // z (g=0) or r (g=1)

        // intra-wave exchange to the candidate lanes
        const float zv = __shfl(gate, ul, 64);       // from z-lane
        const float rv = __shfl(gate, 16 + ul, 64);  // from r-lane

        if (g >= 2) {
            const float hh   = tanh_fast(xw + rv * ah);
            const float hnew = zv * hprev + (1.0f - zv) * hh;
            const float res  = (tok != 0) ? hnew : hprev;   // mask_zero carry
            hprev = res;
            if (g == 2) {
                s_hbuf[(t + 1) & 1][unit] = res;
                gru_out[((size_t)(b * S_ + tt)) * (2 * H_) + dir * H_ + unit] = res;
            }
        }

        __syncthreads();   // new h visible; old-h reads complete (dbuf)
        tok = ntok;
        xw  = xw_next;
    }
}

// x1 = sigmoid(gru_out @ w1 + b1), x2 = sigmoid(gru_out @ w2 + b2)
__global__ __launch_bounds__(256) void head_kernel(
    const float* __restrict__ gru,      // [B*S, 2H]
    const float* __restrict__ w1, const float* __restrict__ b1,
    const float* __restrict__ w2, const float* __restrict__ b2,
    float* __restrict__ x1, float* __restrict__ x2)
{
    __shared__ __align__(16) float s_w1[2 * H_];
    __shared__ __align__(16) float s_w2[2 * H_];
    const int tid = threadIdx.x;
    if (tid < 2 * H_)      s_w1[tid]          = w1[tid];
    else                   s_w2[tid - 2 * H_] = w2[tid - 2 * H_];
    __syncthreads();

    const int i = blockIdx.x * 256 + tid;
    const float4* g4 = (const float4*)(gru + (size_t)i * (2 * H_));
    float a1 = b1[0], a2 = b2[0];
    #pragma unroll
    for (int k = 0; k < (2 * H_) / 4; ++k) {
        const float4 v  = g4[k];
        const float4 q1 = ((const float4*)s_w1)[k];
        const float4 q2 = ((const float4*)s_w2)[k];
        a1 += v.x * q1.x + v.y * q1.y + v.z * q1.z + v.w * q1.w;
        a2 += v.x * q2.x + v.y * q2.y + v.z * q2.z + v.w * q2.w;
    }
    x1[i] = sigmoidf_(a1);
    x2[i] = sigmoidf_(a2);
}

extern "C" void kernel_launch(void* const* d_in, const int* in_sizes, int n_in,
                              void* d_out, int out_size, void* d_ws, size_t ws_size,
                              hipStream_t stream) {
    (void)in_sizes; (void)n_in; (void)ws_size; (void)out_size;

    const int*   inputs = (const int*)  d_in[0];
    const float* emb    = (const float*)d_in[1];
    const float* Wf     = (const float*)d_in[2];
    const float* Uf     = (const float*)d_in[3];
    const float* bif    = (const float*)d_in[4];
    const float* brf    = (const float*)d_in[5];
    const float* Wb     = (const float*)d_in[6];
    const float* Ub     = (const float*)d_in[7];
    const float* bib    = (const float*)d_in[8];
    const float* brb    = (const float*)d_in[9];
    const float* w1     = (const float*)d_in[10];
    const float* b1     = (const float*)d_in[11];
    const float* w2     = (const float*)d_in[12];
    const float* b2     = (const float*)d_in[13];

    float* out = (float*)d_out;
    float* x1  = out;                       // [B*S]
    float* x2  = out + (size_t)B_ * S_;     // [B*S]
    float* gru = out + (size_t)2 * B_ * S_; // [B*S, 2H]

    // workspace: proj [2][V][192] floats, then Ut [2][192][64] floats (~7.77 MB)
    float* proj = (float*)d_ws;
    float* Ut   = proj + (size_t)2 * V_ * G3;

    proj_kernel<<<dim3((V_ + VCHUNK - 1) / VCHUNK, 2), 192, 0, stream>>>(
        emb, Wf, bif, Wb, bib, proj);
    utrans_kernel<<<2, 256, 0, stream>>>(Uf, Ub, Ut);

    gru_scan3<<<B_ * 2, 256, 0, stream>>>(inputs, proj, Ut, brf, brb, gru);

    head_kernel<<<(B_ * S_) / 256, 256, 0, stream>>>(gru, w1, b1, w2, b2, x1, x2);
}

// Round 5
// 288.725 us; speedup vs baseline: 1.4304x; 1.1064x over previous
//
#include <hip/hip_runtime.h>
#include <hip/hip_bf16.h>

#define B_  128
#define S_  512
#define H_  64
#define E_  64
#define G3  192   // 3*H
#define V_  4996
#define VCHUNK 32
#define CHUNK  32            // time steps staged per LDS chunk
#define NCHUNK (S_ / CHUNK)  // 16

typedef float f32x2 __attribute__((ext_vector_type(2)));
typedef float f32x4 __attribute__((ext_vector_type(4)));

__device__ __forceinline__ float sigmoidf_(float x) {
    return 1.0f / (1.0f + __expf(-x));
}

__device__ __forceinline__ float tanh_fast(float x) {
    x = fminf(fmaxf(x, -15.0f), 15.0f);
    const float e = __expf(2.0f * x);
    return (e - 1.0f) / (e + 1.0f);
}

// ---------------------------------------------------------------------------
// Kernel 1: pre-project the embedding table through the input kernels.
//   proj[dir][v][j] = sum_e emb[v][e] * W_dir[e][j] + bi_dir[j]
// ---------------------------------------------------------------------------
__global__ __launch_bounds__(192) void proj_kernel(
    const float* __restrict__ emb,
    const float* __restrict__ Wf, const float* __restrict__ bif,
    const float* __restrict__ Wb, const float* __restrict__ bib,
    float* __restrict__ proj)            // [2][V][192]
{
    const int dir = blockIdx.y;
    const float* W  = dir ? Wb  : Wf;
    const float* bi = dir ? bib : bif;
    const int v0 = blockIdx.x * VCHUNK;
    const int j  = threadIdx.x;
    const int nrows = min(VCHUNK, V_ - v0);

    __shared__ __align__(16) float s_e[VCHUNK * E_];
    for (int i = j; i < nrows * E_; i += 192) s_e[i] = emb[(size_t)v0 * E_ + i];

    float wcol[E_];
    #pragma unroll
    for (int e = 0; e < E_; ++e) wcol[e] = W[e * G3 + j];
    const float bij = bi[j];
    __syncthreads();

    for (int r = 0; r < nrows; ++r) {
        const float4* x4 = (const float4*)(s_e + r * E_);
        float a0 = 0.f, a1 = 0.f, a2 = 0.f, a3 = 0.f;
        #pragma unroll
        for (int e4 = 0; e4 < 16; e4 += 4) {
            float4 h0 = x4[e4], h1 = x4[e4+1], h2 = x4[e4+2], h3 = x4[e4+3];
            a0 = fmaf(h0.x, wcol[4*e4+ 0], a0); a0 = fmaf(h0.y, wcol[4*e4+ 1], a0);
            a0 = fmaf(h0.z, wcol[4*e4+ 2], a0); a0 = fmaf(h0.w, wcol[4*e4+ 3], a0);
            a1 = fmaf(h1.x, wcol[4*e4+ 4], a1); a1 = fmaf(h1.y, wcol[4*e4+ 5], a1);
            a1 = fmaf(h1.z, wcol[4*e4+ 6], a1); a1 = fmaf(h1.w, wcol[4*e4+ 7], a1);
            a2 = fmaf(h2.x, wcol[4*e4+ 8], a2); a2 = fmaf(h2.y, wcol[4*e4+ 9], a2);
            a2 = fmaf(h2.z, wcol[4*e4+10], a2); a2 = fmaf(h2.w, wcol[4*e4+11], a2);
            a3 = fmaf(h3.x, wcol[4*e4+12], a3); a3 = fmaf(h3.y, wcol[4*e4+13], a3);
            a3 = fmaf(h3.z, wcol[4*e4+14], a3); a3 = fmaf(h3.w, wcol[4*e4+15], a3);
        }
        proj[((size_t)dir * V_ + v0 + r) * G3 + j] = ((a0 + a1) + (a2 + a3)) + bij;
    }
}

// Kernel 2: transpose recurrent kernels: Ut[dir][j][e] = U_dir[e][j]
__global__ void utrans_kernel(const float* __restrict__ Uf,
                              const float* __restrict__ Ub,
                              float* __restrict__ Ut)   // [2][192][64]
{
    const int dir = blockIdx.x;
    const float* U = dir ? Ub : Uf;
    float* o = Ut + (size_t)dir * G3 * H_;
    for (int k = threadIdx.x; k < G3 * H_; k += blockDim.x) {
        const int j = k / H_, e = k % H_;
        o[k] = U[e * G3 + j];
    }
}

// ---------------------------------------------------------------------------
// Kernel 3: the sequential scan. One block per (batch row, direction).
// 256 threads = 4 waves; lane = g*16+ul, g=0:z g=1:r g=2:candidate g=3:dup.
// Steady-state loop touches ONLY LDS+VALU: xw comes from a 32-step LDS chunk
// (staged once per chunk), outputs buffered in LDS and flushed per chunk —
// so per-step __syncthreads() never drains vmem (the vmcnt(0) barrier-drain
// was the R3 bottleneck).
// ---------------------------------------------------------------------------
__global__ __launch_bounds__(256)
__attribute__((amdgpu_waves_per_eu(1, 1)))
void gru_scan4(
    const int*   __restrict__ inputs,   // [B,S]
    const float* __restrict__ proj,     // [2][V][192]
    const float* __restrict__ Ut,       // [2][192][64]
    const float* __restrict__ brf, const float* __restrict__ brb,
    float* __restrict__ gru_out)        // [B,S,2H]
{
    const int b    = blockIdx.x >> 1;
    const int dir  = blockIdx.x & 1;
    const int tid  = threadIdx.x;
    const int lane = tid & 63;
    const int wv   = tid >> 6;             // 0..3
    const int g    = lane >> 4;            // 0=z, 1=r, 2=c, 3=dup
    const int ul   = lane & 15;
    const int unit = wv * 16 + ul;         // 0..63
    const int j    = (g >= 2 ? 2 : g) * H_ + unit;   // gate column

    const float* eproj = proj + (size_t)dir * V_ * G3;
    const float* br    = dir ? brb : brf;

    __shared__ int s_idx[S_];
    __shared__ __align__(16) float s_h[2][H_];
    __shared__ __align__(16) float s_xw[2][CHUNK][G3];   // 49 KB
    __shared__ __align__(16) float s_hist[CHUNK][H_];    // 8 KB

    for (int t2 = tid; t2 < S_; t2 += 256) s_idx[t2] = inputs[b * S_ + t2];
    if (tid < H_) s_h[0][tid] = 0.0f;

    // Recurrent column in registers: 16 f32x4 = 64 VGPRs.
    f32x4 u4[16];
    {
        const f32x4* p = (const f32x4*)(Ut + ((size_t)dir * G3 + j) * H_);
        #pragma unroll
        for (int k = 0; k < 16; ++k) u4[k] = p[k];
        #pragma unroll
        for (int k = 0; k < 16; ++k) asm volatile("" : "+v"(u4[k]));
    }
    const float brj   = br[j];
    float       hprev = 0.0f;

    __syncthreads();   // s_idx ready (staging reads it)

    // ---- staging helpers (6 f32x4 per thread = one 32-step chunk) ----
    f32x4 st[6];
    auto stage_load = [&](int c) {
        const int base = c * CHUNK;
        #pragma unroll
        for (int k = 0; k < 6; ++k) {
            const int idx  = tid + 256 * k;        // 0..1535
            const int row  = idx / 48;             // step-in-chunk
            const int seg  = idx - row * 48;       // float4 seg in row
            const int step = base + row;
            const int tt2  = dir ? (S_ - 1 - step) : step;
            const int tk   = s_idx[tt2];
            st[k] = *(const f32x4*)(eproj + (size_t)tk * G3 + seg * 4);
        }
        #pragma unroll
        for (int k = 0; k < 6; ++k) asm volatile("" : "+v"(st[k]));
    };
    auto stage_write = [&](int buf) {
        #pragma unroll
        for (int k = 0; k < 6; ++k) {
            const int idx = tid + 256 * k;
            const int row = idx / 48;
            const int seg = idx - row * 48;
            *(f32x4*)(&s_xw[buf][row][seg * 4]) = st[k];
        }
    };

    stage_load(0);
    stage_write(0);
    __syncthreads();   // chunk 0 ready

    for (int c = 0; c < NCHUNK; ++c) {
        const int cb = c & 1;
        if (c + 1 < NCHUNK) stage_load(c + 1);   // in flight across the chunk
        const float* xwrow = &s_xw[cb][0][0];

        for (int t0 = 0; t0 < CHUNK; ++t0) {
            const int t   = c * CHUNK + t0;
            const int tt  = dir ? (S_ - 1 - t) : t;
            const int tok = s_idx[tt];
            const float xw = xwrow[t0 * G3 + j];

            // rec_j = br_j + h . U[:,j] — packed f32x2 FMAs, 4 indep chains
            const f32x4* h4 = (const f32x4*)s_h[t & 1];
            f32x2 aA = {0.f, 0.f}, aB = {0.f, 0.f}, aC = {0.f, 0.f}, aD = {0.f, 0.f};
            #pragma unroll
            for (int k = 0; k < 16; k += 2) {
                const f32x4 h0 = h4[k], h1 = h4[k + 1];
                aA += h0.xy * u4[k].xy;
                aB += h0.zw * u4[k].zw;
                aC += h1.xy * u4[k + 1].xy;
                aD += h1.zw * u4[k + 1].zw;
            }
            const f32x2 sv = (aA + aB) + (aC + aD);
            const float ah = sv.x + sv.y + brj;

            const float gate = sigmoidf_(xw + ah);       // z (g=0) / r (g=1)
            const float zv = __shfl(gate, ul, 64);       // from z-lane
            const float rv = __shfl(gate, 16 + ul, 64);  // from r-lane

            if (g >= 2) {
                const float hh   = tanh_fast(xw + rv * ah);
                const float hnew = zv * hprev + (1.0f - zv) * hh;
                const float res  = (tok != 0) ? hnew : hprev;   // mask_zero
                hprev = res;
                if (g == 2) {
                    s_h[(t + 1) & 1][unit] = res;
                    s_hist[t0][unit]       = res;
                }
            }
            __syncthreads();   // lgkm-only drain in steady state
        }

        // ---- chunk epilogue: flush hist to global, publish staged chunk ----
        #pragma unroll
        for (int q = 0; q < 2; ++q) {
            const int idx  = tid * 2 + q;          // 0..511
            const int r    = idx >> 4;             // step-in-chunk
            const int seg  = idx & 15;             // float4 seg in 64
            const int step = c * CHUNK + r;
            const int tt2  = dir ? (S_ - 1 - step) : step;
            *(float4*)(gru_out + ((size_t)(b * S_ + tt2)) * (2 * H_)
                       + dir * H_ + seg * 4) = *(const float4*)(&s_hist[r][seg * 4]);
        }
        if (c + 1 < NCHUNK) stage_write(cb ^ 1);
        __syncthreads();   // drains chunk's stores+loads ONCE, not per step
    }
}

// x1 = sigmoid(gru_out @ w1 + b1), x2 = sigmoid(gru_out @ w2 + b2)
__global__ __launch_bounds__(256) void head_kernel(
    const float* __restrict__ gru,      // [B*S, 2H]
    const float* __restrict__ w1, const float* __restrict__ b1,
    const float* __restrict__ w2, const float* __restrict__ b2,
    float* __restrict__ x1, float* __restrict__ x2)
{
    __shared__ __align__(16) float s_w1[2 * H_];
    __shared__ __align__(16) float s_w2[2 * H_];
    const int tid = threadIdx.x;
    if (tid < 2 * H_)      s_w1[tid]          = w1[tid];
    else                   s_w2[tid - 2 * H_] = w2[tid - 2 * H_];
    __syncthreads();

    const int i = blockIdx.x * 256 + tid;
    const float4* g4 = (const float4*)(gru + (size_t)i * (2 * H_));
    float a1 = b1[0], a2 = b2[0];
    #pragma unroll
    for (int k = 0; k < (2 * H_) / 4; ++k) {
        const float4 v  = g4[k];
        const float4 q1 = ((const float4*)s_w1)[k];
        const float4 q2 = ((const float4*)s_w2)[k];
        a1 += v.x * q1.x + v.y * q1.y + v.z * q1.z + v.w * q1.w;
        a2 += v.x * q2.x + v.y * q2.y + v.z * q2.z + v.w * q2.w;
    }
    x1[i] = sigmoidf_(a1);
    x2[i] = sigmoidf_(a2);
}

extern "C" void kernel_launch(void* const* d_in, const int* in_sizes, int n_in,
                              void* d_out, int out_size, void* d_ws, size_t ws_size,
                              hipStream_t stream) {
    (void)in_sizes; (void)n_in; (void)ws_size; (void)out_size;

    const int*   inputs = (const int*)  d_in[0];
    const float* emb    = (const float*)d_in[1];
    const float* Wf     = (const float*)d_in[2];
    const float* Uf     = (const float*)d_in[3];
    const float* bif    = (const float*)d_in[4];
    const float* brf    = (const float*)d_in[5];
    const float* Wb     = (const float*)d_in[6];
    const float* Ub     = (const float*)d_in[7];
    const float* bib    = (const float*)d_in[8];
    const float* brb    = (const float*)d_in[9];
    const float* w1     = (const float*)d_in[10];
    const float* b1     = (const float*)d_in[11];
    const float* w2     = (const float*)d_in[12];
    const float* b2     = (const float*)d_in[13];

    float* out = (float*)d_out;
    float* x1  = out;                       // [B*S]
    float* x2  = out + (size_t)B_ * S_;     // [B*S]
    float* gru = out + (size_t)2 * B_ * S_; // [B*S, 2H]

    // workspace: proj [2][V][192] floats, then Ut [2][192][64] floats (~7.77 MB)
    float* proj = (float*)d_ws;
    float* Ut   = proj + (size_t)2 * V_ * G3;

    proj_kernel<<<dim3((V_ + VCHUNK - 1) / VCHUNK, 2), 192, 0, stream>>>(
        emb, Wf, bif, Wb, bib, proj);
    utrans_kernel<<<2, 256, 0, stream>>>(Uf, Ub, Ut);

    gru_scan4<<<B_ * 2, 256, 0, stream>>>(inputs, proj, Ut, brf, brb, gru);

    head_kernel<<<(B_ * S_) / 256, 256, 0, stream>>>(gru, w1, b1, w2, b2, x1, x2);
}